// Round 13
// baseline (1202.108 us; speedup 1.0000x reference)
//
#include <hip/hip_runtime.h>

static constexpr int L_ = 2;      // layers
static constexpr int H_ = 1024;   // hidden
static constexpr int E_ = 1024;   // embedding
static constexpr int T_ = 64;     // steps
static constexpr int NB = 256;    // blocks (== CUs)
static constexpr int BT = 1024;   // threads per block (16 waves)

// Dataflow payload — write-once per-step slots, single copy (R11: replication
// is perf-neutral). Sentinel 0xFF per call; produced values are finite, so
// "bits != 0xFFFFFFFF" == ready. Plain relaxed agent stores (R10: xchg
// writes through to HBM and regresses).
static constexpr int WS_XV = 0;                       // xv[T+1][H]
static constexpr int WS_HH = WS_XV + (T_ + 1) * H_;   // h[T][L][H]
static constexpr int WS_LG = WS_HH + T_ * L_ * H_;    // lg[T][E]
static constexpr size_t WS_BYTES = (size_t)(WS_LG + T_ * E_) * 4;

static constexpr unsigned SENT = 0xFFFFFFFFu;

__device__ __forceinline__ float sigm(float v) { return 1.0f / (1.0f + expf(-v)); }

__device__ __forceinline__ void cstore(float* p, float v) {
  __hip_atomic_store(p, v, __ATOMIC_RELAXED, __HIP_MEMORY_SCOPE_AGENT);
}
__device__ __forceinline__ unsigned long long cload64(const unsigned long long* p) {
  return __hip_atomic_load(p, __ATOMIC_RELAXED, __HIP_MEMORY_SCOPE_AGENT);
}

// Poll 4 contiguous words (16B-aligned) until all are non-sentinel.
__device__ __forceinline__ float4 poll4(const float* p4) {
  const unsigned long long* p = (const unsigned long long*)p4;
  unsigned long long a = cload64(p), c = cload64(p + 1);
  while (((unsigned)a == SENT) | ((unsigned)(a >> 32) == SENT) |
         ((unsigned)c == SENT) | ((unsigned)(c >> 32) == SENT)) {
    __builtin_amdgcn_s_sleep(1);
    a = cload64(p); c = cload64(p + 1);
  }
  float4 v;
  v.x = __uint_as_float((unsigned)a);
  v.y = __uint_as_float((unsigned)(a >> 32));
  v.z = __uint_as_float((unsigned)c);
  v.w = __uint_as_float((unsigned)(c >> 32));
  return v;
}

// Raw block barrier: LDS-drain only, NEVER vmcnt. hipcc's __syncthreads
// emits s_waitcnt vmcnt(0) before s_barrier (drains the We prefetch stream
// into every phase boundary — the R8-R11 hidden serializer). This one
// keeps global loads/stores in flight across phases.
__device__ __forceinline__ void bar_lds() {
  asm volatile("s_waitcnt lgkmcnt(0)" ::: "memory");
  __builtin_amdgcn_s_barrier();
  asm volatile("" ::: "memory");
}

// Weight-stationary, barrier-light persistent controller (R8 dataflow).
// Wave w of block b permanently holds, pinned in 64 registers:
//   role (l = w>>3, q = (w>>1)&3, half = w&1 : 0=W_ih, 1=W_hh),
//   rows j = 4b+u (u=0..3), columns k = m*256 + lane*4 + {0..3}.
// Strict vmem role partition (so no wait chain crosses roles):
//   waves 0-3  (tid<256): pollers — only in-loop vmem is the poll loads
//   wave  4    (lanes 0-3): service — epilogues, logits/xv publish, out
//                           (stores only, fire-and-forget, never drained)
//   waves 8-15 (tid>=512): We holders — prefetch HBM loads, stage to LDS
// Phase schedule (4 chip-wide hops/step, prep-dots hoisted as in R8):
//   A: poll xv(t); holders stage We(t)->LDS, then issue We(t+1) loads;
//      l0 x-half dot; service publishes h0(t)
//   B: poll h0(t); l1 x-half (critical) + l0 h-half (t+1); publish h1(t)
//   C: poll h1(t); logits rows + l1 h-half (t+1); publish lg(t)
//   D: poll lg(t); softmax + out + feedback; publish xv(t+1)
__global__ __launch_bounds__(BT, 4) void ctrl_kernel(
    const float* __restrict__ W_ih, const float* __restrict__ W_hh,
    const float* __restrict__ b_ih, const float* __restrict__ b_hh,
    const float* __restrict__ We,   const float* __restrict__ be,
    float* __restrict__ out, float* __restrict__ ws)
{
  const int tid  = threadIdx.x;
  const int b    = blockIdx.x;
  const int lane = tid & 63;
  const int w    = tid >> 6;       // wave 0..15
  const int wl   = w >> 3;         // layer of this wave's weights
  const int wq   = (w >> 1) & 3;   // gate index (i,f,g,o)
  const int wh   = w & 1;          // 0: W_ih half, 1: W_hh half

  float* XV = ws + WS_XV;
  float* HH = ws + WS_HH;
  float* LG = ws + WS_LG;

  // feedback column ownership, XCD-swizzled (bijective over blocks)
  const int cswz = ((b & 7) * 32 + (b >> 3)) * 4;

  __shared__ float  s_x[H_];            // staging: x / h0 / h1 / logits
  __shared__ float  s_wlog[4 * H_];     // We_t rows 4b..4b+3
  __shared__ float  s_wfb[4 * H_];      // We_t cols cswz..cswz+3
  __shared__ float  s_gd[2][4][2][4];   // gate partials [l][q][half][unit]
  __shared__ float  s_bias[2][4][4];    // combined biases [l][q][unit]
  __shared__ float  s_be[T_ * 4];       // be rows for this block, all steps
  __shared__ float  s_c[2][4];          // cell state [l][unit]
  __shared__ float  s_red[16];          // logits reduction scratch
  __shared__ float  s_redm[16];         // softmax max partials
  __shared__ float  s_reds[16];         // softmax sum partials
  __shared__ float4 s_part4[16];        // x_next per-wave partials

  // ---- prologue ----
  if (tid < 32) {
    const int l = tid >> 4, q = (tid >> 2) & 3, u = tid & 3;
    const int j = b * 4 + u;
    s_bias[l][q][u] = b_ih[(size_t)l * 4 * H_ + q * H_ + j]
                    + b_hh[(size_t)l * 4 * H_ + q * H_ + j];
  }
  if (tid < 8) s_c[tid >> 2][tid & 3] = 0.0f;
  if (tid < 64) ((float*)s_gd)[tid] = 0.0f;   // h-half partials start at 0
  if (tid < T_ * 4)
    s_be[tid] = be[(size_t)(tid >> 2) * E_ + b * 4 + (tid & 3)];

  float4 wr[4][4];
  {
    const float* Wbase = (wh == 0) ? W_ih : W_hh;
    #pragma unroll
    for (int u = 0; u < 4; ++u) {
      const size_t row = (size_t)wl * 4 * H_ * H_
                       + ((size_t)wq * H_ + (size_t)(b * 4 + u)) * (size_t)H_;
      #pragma unroll
      for (int m = 0; m < 4; ++m)
        wr[u][m] = *(const float4*)&Wbase[row + (size_t)m * 256 + lane * 4];
    }
  }
  #pragma unroll
  for (int u = 0; u < 4; ++u)
    #pragma unroll
    for (int m = 0; m < 4; ++m)
      asm volatile("" : "+v"(wr[u][m].x), "+v"(wr[u][m].y),
                        "+v"(wr[u][m].z), "+v"(wr[u][m].w));

  // holders: hj in [0,512) holds f4 elems {hj, hj+512} of wlog and wfb
  const int hj = tid - 512;
  const bool holder = hj >= 0;
  float4 r_lg0, r_lg1, r_fb0, r_fb1;
  if (holder) {   // step-0 We operands
    r_lg0 = *(const float4*)&We[((size_t)(b * 4 + (hj >> 8))) * H_ + (hj & 255) * 4];
    r_lg1 = *(const float4*)&We[((size_t)(b * 4 + ((hj + 512) >> 8))) * H_ + ((hj + 512) & 255) * 4];
    r_fb0 = *(const float4*)&We[(size_t)hj * H_ + cswz];
    r_fb1 = *(const float4*)&We[(size_t)(hj + 512) * H_ + cswz];
  }

  // dot of this wave's held weight strip against s_x, into s_gd[dl][dq][dh]
  auto dot_to = [&](int dl, int dq, int dh) {
    const float4* vin = (const float4*)s_x;
    float a0 = 0.f, a1 = 0.f, a2 = 0.f, a3 = 0.f;
    #pragma unroll
    for (int m = 0; m < 4; ++m) {
      const float4 x4 = vin[m * 64 + lane];
      a0 += wr[0][m].x * x4.x + wr[0][m].y * x4.y + wr[0][m].z * x4.z + wr[0][m].w * x4.w;
      a1 += wr[1][m].x * x4.x + wr[1][m].y * x4.y + wr[1][m].z * x4.z + wr[1][m].w * x4.w;
      a2 += wr[2][m].x * x4.x + wr[2][m].y * x4.y + wr[2][m].z * x4.z + wr[2][m].w * x4.w;
      a3 += wr[3][m].x * x4.x + wr[3][m].y * x4.y + wr[3][m].z * x4.z + wr[3][m].w * x4.w;
    }
    #pragma unroll
    for (int off = 32; off; off >>= 1) {
      a0 += __shfl_down(a0, off, 64);
      a1 += __shfl_down(a1, off, 64);
      a2 += __shfl_down(a2, off, 64);
      a3 += __shfl_down(a3, off, 64);
    }
    if (lane == 0) {
      s_gd[dl][dq][dh][0] = a0; s_gd[dl][dq][dh][1] = a1;
      s_gd[dl][dq][dh][2] = a2; s_gd[dl][dq][dh][3] = a3;
    }
  };

  // LSTM epilogue for layer l (service lanes 0-3 of wave 4), publishes h
  auto epilogue = [&](int l, int t) {
    if (w == 4 && lane < 4) {
      const int u = lane;
      const float g0 = s_gd[l][0][0][u] + s_gd[l][0][1][u] + s_bias[l][0][u];
      const float g1 = s_gd[l][1][0][u] + s_gd[l][1][1][u] + s_bias[l][1][u];
      const float g2 = s_gd[l][2][0][u] + s_gd[l][2][1][u] + s_bias[l][2][u];
      const float g3 = s_gd[l][3][0][u] + s_gd[l][3][1][u] + s_bias[l][3][u];
      const float cn = sigm(g1) * s_c[l][u] + sigm(g0) * tanhf(g2);
      s_c[l][u] = cn;
      cstore(&HH[((size_t)t * L_ + l) * H_ + b * 4 + u], sigm(g3) * tanhf(cn));
    }
  };

  for (int t = 0; t < T_; ++t) {
    // ===== phase A: poll xv(t); holders stage We(t) + issue We(t+1) =====
    if (t == 0) {
      if (tid < 256) *(float4*)&s_x[4 * tid] = make_float4(0.f, 0.f, 0.f, 0.f);
    } else if (tid < 256) {
      const float4 v = poll4(&XV[(size_t)t * H_ + 4 * tid]);
      *(float4*)&s_x[4 * tid] = v;
    }
    if (holder) {   // 16B-stride ds_writes: conflict-free
      *(float4*)&s_wlog[hj * 4]         = r_lg0;
      *(float4*)&s_wlog[(hj + 512) * 4] = r_lg1;
      *(float4*)&s_wfb[hj * 4]          = r_fb0;
      *(float4*)&s_wfb[(hj + 512) * 4]  = r_fb1;
    }
    bar_lds();
    if (wl == 0 && wh == 0) dot_to(0, wq, 0);
    bar_lds();
    epilogue(0, t);   // publish h0(t)
    // holders issue next step's prefetch here: a full step in flight before
    // the ds_write consumes it; never drained by any barrier (raw barriers)
    if (holder && t + 1 < T_) {
      const float* Wn = We + (size_t)(t + 1) * E_ * H_;
      r_lg0 = *(const float4*)&Wn[((size_t)(b * 4 + (hj >> 8))) * H_ + (hj & 255) * 4];
      r_lg1 = *(const float4*)&Wn[((size_t)(b * 4 + ((hj + 512) >> 8))) * H_ + ((hj + 512) & 255) * 4];
      r_fb0 = *(const float4*)&Wn[(size_t)hj * H_ + cswz];
      r_fb1 = *(const float4*)&Wn[(size_t)(hj + 512) * H_ + cswz];
    }

    // ===== phase B: poll h0(t); l1 x-half (critical) + l0 h-half (t+1) =====
    if (tid < 256) {
      const float4 v = poll4(&HH[((size_t)t * L_ + 0) * H_ + 4 * tid]);
      *(float4*)&s_x[4 * tid] = v;
    }
    bar_lds();
    if (wl == 1 && wh == 0) dot_to(1, wq, 0);  // critical
    if (wl == 0 && wh == 1) dot_to(0, wq, 1);  // for t+1
    bar_lds();
    epilogue(1, t);   // publish h1(t)

    // ===== phase C: poll h1(t); logits rows + l1 h-half (t+1) =====
    if (tid < 256) {
      const float4 v = poll4(&HH[((size_t)t * L_ + 1) * H_ + 4 * tid]);
      *(float4*)&s_x[4 * tid] = v;
    }
    bar_lds();
    {
      const float4 wl4 = *(const float4*)&s_wlog[tid * 4];
      const float4 h4  = ((const float4*)s_x)[tid & 255];
      float a = wl4.x * h4.x + wl4.y * h4.y + wl4.z * h4.z + wl4.w * h4.w;
      #pragma unroll
      for (int off = 32; off; off >>= 1) a += __shfl_down(a, off, 64);
      if (lane == 0) s_red[w] = a;
    }
    if (wl == 1 && wh == 1) dot_to(1, wq, 1);  // for t+1
    bar_lds();
    if (w == 4 && lane < 4) {   // service: sum row partials -> publish logits
      const float v = s_red[lane * 4] + s_red[lane * 4 + 1] + s_red[lane * 4 + 2]
                    + s_red[lane * 4 + 3] + s_be[t * 4 + lane];
      cstore(&LG[(size_t)t * E_ + b * 4 + lane], v);
    }

    // ===== phase D: poll lg(t); softmax + out + feedback; publish xv(t+1) =====
    if (tid < 256) {
      const float4 v = poll4(&LG[(size_t)t * E_ + 4 * tid]);
      *(float4*)&s_x[4 * tid] = v;
    }
    bar_lds();
    {
      const float v = s_x[tid];
      float mm = v;
      #pragma unroll
      for (int off = 32; off; off >>= 1) mm = fmaxf(mm, __shfl_down(mm, off, 64));
      if (lane == 0) s_redm[w] = mm;
      bar_lds();
      mm = s_redm[0];
      #pragma unroll
      for (int k = 1; k < 16; ++k) mm = fmaxf(mm, s_redm[k]);
      const float ev = expf(v - mm);        // e = tid
      float sv = ev;
      #pragma unroll
      for (int off = 32; off; off >>= 1) sv += __shfl_down(sv, off, 64);
      if (lane == 0) s_reds[w] = sv;
      bar_lds();
      float ssum = 0.f;
      #pragma unroll
      for (int k = 0; k < 16; ++k) ssum += s_reds[k];
      const float inv = 1.0f / ssum;
      const float d = ev * inv;             // decision[e = tid], all blocks agree

      if (w == 4 && lane < 4)   // service writes block b's 4 outputs
        out[(size_t)t * E_ + b * 4 + lane] = expf(s_x[b * 4 + lane] - mm) * inv;

      const float4 w4 = *(const float4*)&s_wfb[tid * 4];
      float4 acc = make_float4(d * w4.x, d * w4.y, d * w4.z, d * w4.w);
      #pragma unroll
      for (int off = 32; off; off >>= 1) {
        acc.x += __shfl_down(acc.x, off, 64);
        acc.y += __shfl_down(acc.y, off, 64);
        acc.z += __shfl_down(acc.z, off, 64);
        acc.w += __shfl_down(acc.w, off, 64);
      }
      if (lane == 0) s_part4[w] = acc;
      bar_lds();
      if (w == 4 && lane < 4) {
        float s = 0.f;
        #pragma unroll
        for (int k = 0; k < 16; ++k)
          s += ((const float*)&s_part4[k])[lane];
        cstore(&XV[(size_t)(t + 1) * H_ + cswz + lane], s);  // x for t+1
      }
    }
  }
}

extern "C" void kernel_launch(void* const* d_in, const int* in_sizes, int n_in,
                              void* d_out, int out_size, void* d_ws, size_t ws_size,
                              hipStream_t stream) {
  const float* W_ih = (const float*)d_in[0];
  const float* W_hh = (const float*)d_in[1];
  const float* b_ih = (const float*)d_in[2];
  const float* b_hh = (const float*)d_in[3];
  const float* We   = (const float*)d_in[4];
  const float* be   = (const float*)d_in[5];
  float* out = (float*)d_out;
  float* ws  = (float*)d_ws;

  // sentinel-fill all dataflow slots (graph-capturable, replayed every call)
  (void)hipMemsetAsync(ws, 0xFF, WS_BYTES, stream);

  void* args[] = {(void*)&W_ih, (void*)&W_hh, (void*)&b_ih, (void*)&b_hh,
                  (void*)&We,   (void*)&be,   (void*)&out,  (void*)&ws};
  (void)hipLaunchCooperativeKernel((const void*)ctrl_kernel, dim3(NB), dim3(BT),
                                   args, 0, stream);
}

// Round 14
// 1051.529 us; speedup vs baseline: 1.1432x; 1.1432x over previous
//
#include <hip/hip_runtime.h>

static constexpr int L_ = 2;      // layers
static constexpr int H_ = 1024;   // hidden
static constexpr int E_ = 1024;   // embedding
static constexpr int T_ = 64;     // steps
static constexpr int NB = 256;    // blocks (== CUs)
static constexpr int BT = 1024;   // threads per block (16 waves)

// Dataflow payload — write-once per-step slots (R8 layout). Sentinel 0xFF per
// call; all produced values are finite, so "bits != 0xFFFFFFFF" == ready.
// Plain relaxed agent stores (R10: xchg regresses; R11: replication null).
static constexpr int WS_XV = 0;                       // xv[T+1][H]
static constexpr int WS_HH = WS_XV + (T_ + 1) * H_;   // h[T][L][H]
static constexpr int WS_LG = WS_HH + T_ * L_ * H_;    // lg[T][E]
static constexpr size_t WS_BYTES = (size_t)(WS_LG + T_ * E_) * 4;

static constexpr unsigned SENT = 0xFFFFFFFFu;

__device__ __forceinline__ float sigm(float v) { return 1.0f / (1.0f + expf(-v)); }

__device__ __forceinline__ void cstore(float* p, float v) {
  __hip_atomic_store(p, v, __ATOMIC_RELAXED, __HIP_MEMORY_SCOPE_AGENT);
}
__device__ __forceinline__ unsigned long long cload64(const unsigned long long* p) {
  return __hip_atomic_load(p, __ATOMIC_RELAXED, __HIP_MEMORY_SCOPE_AGENT);
}

// Poll 4 contiguous words (16B-aligned) until all are non-sentinel.
__device__ __forceinline__ float4 poll4(const float* p4) {
  const unsigned long long* p = (const unsigned long long*)p4;
  unsigned long long a = cload64(p), c = cload64(p + 1);
  while (((unsigned)a == SENT) | ((unsigned)(a >> 32) == SENT) |
         ((unsigned)c == SENT) | ((unsigned)(c >> 32) == SENT)) {
    __builtin_amdgcn_s_sleep(1);
    a = cload64(p); c = cload64(p + 1);
  }
  float4 v;
  v.x = __uint_as_float((unsigned)a);
  v.y = __uint_as_float((unsigned)(a >> 32));
  v.z = __uint_as_float((unsigned)c);
  v.w = __uint_as_float((unsigned)(c >> 32));
  return v;
}

// Weight-stationary, barrier-free-dataflow persistent controller (= the
// 997us R8 kernel + proven micro-wins: fused 1-pass no-max phase D,
// 16-lane parallel epilogue, be in LDS, float4 pollers).
// Wave w of block b permanently holds, pinned in 64 registers:
//   role (l = w>>3, q = (w>>1)&3, half = w&1 : 0=W_ih, 1=W_hh),
//   rows j = 4b+u (u=0..3), columns k = m*256 + lane*4 + {0..3}.
// Phase schedule (4 chip-wide hops/step — structurally minimal):
//   A: poll xv(t)  -> l0 x-half dots                -> publish h0(t)
//   B: poll h0(t)  -> l1 x-half [crit] + l0 h-half (t+1) -> publish h1(t)
//   C: poll h1(t)  -> logits rows + l1 h-half (t+1)      -> publish lg(t)
//   D: poll lg(t)  -> fused exp+feedback reduce + out    -> publish xv(t+1)
//   then all threads issue We(t+1) prefetch (drains at next phase-A poll).
__global__ __launch_bounds__(BT, 4) void ctrl_kernel(
    const float* __restrict__ W_ih, const float* __restrict__ W_hh,
    const float* __restrict__ b_ih, const float* __restrict__ b_hh,
    const float* __restrict__ We,   const float* __restrict__ be,
    float* __restrict__ out, float* __restrict__ ws)
{
  const int tid  = threadIdx.x;
  const int b    = blockIdx.x;
  const int lane = tid & 63;
  const int w    = tid >> 6;       // wave 0..15
  const int wl   = w >> 3;         // layer of this wave's weights
  const int wq   = (w >> 1) & 3;   // gate index (i,f,g,o)
  const int wh   = w & 1;          // 0: W_ih half, 1: W_hh half

  float* XV = ws + WS_XV;
  float* HH = ws + WS_HH;
  float* LG = ws + WS_LG;

  // feedback column ownership, XCD-swizzled (bijective over 256 blocks)
  const int cswz = ((b & 7) * 32 + (b >> 3)) * 4;

  __shared__ float  s_x[H_];            // staging: x / h0 / h1 / logits
  __shared__ float  s_gd[2][4][2][4];   // gate partials [l][q][half][unit]
  __shared__ float  s_bias[2][4][4];    // combined biases [l][q][unit]
  __shared__ float  s_be[T_ * 4];       // be rows for this block, all steps
  __shared__ float  s_c[2][4];          // cell state [l][unit]
  __shared__ float  s_red[16];          // logits reduction scratch
  __shared__ float  s_reds[16];         // softmax sum partials
  __shared__ float4 s_part4[16];        // x_next per-wave partials

  // ---- prologue ----
  if (tid < 32) {
    const int l = tid >> 4, q = (tid >> 2) & 3, u = tid & 3;
    const int j = b * 4 + u;
    s_bias[l][q][u] = b_ih[(size_t)l * 4 * H_ + q * H_ + j]
                    + b_hh[(size_t)l * 4 * H_ + q * H_ + j];
  }
  if (tid < 8) s_c[tid >> 2][tid & 3] = 0.0f;
  if (tid < 64) ((float*)s_gd)[tid] = 0.0f;   // h-half partials start at 0
  if (tid < T_ * 4)   // be[t][b*4+u] -> LDS (off the logits critical path)
    s_be[tid] = be[(size_t)(tid >> 2) * E_ + b * 4 + (tid & 3)];

  float4 wr[4][4];
  {
    const float* Wbase = (wh == 0) ? W_ih : W_hh;
    #pragma unroll
    for (int u = 0; u < 4; ++u) {
      const size_t row = (size_t)wl * 4 * H_ * H_
                       + ((size_t)wq * H_ + (size_t)(b * 4 + u)) * (size_t)H_;
      #pragma unroll
      for (int m = 0; m < 4; ++m)
        wr[u][m] = *(const float4*)&Wbase[row + (size_t)m * 256 + lane * 4];
    }
  }
  #pragma unroll
  for (int u = 0; u < 4; ++u)
    #pragma unroll
    for (int m = 0; m < 4; ++m)
      asm volatile("" : "+v"(wr[u][m].x), "+v"(wr[u][m].y),
                        "+v"(wr[u][m].z), "+v"(wr[u][m].w));

  // dot of this wave's held weight strip against s_x, into s_gd[dl][dq][dh]
  auto dot_to = [&](int dl, int dq, int dh) {
    const float4* vin = (const float4*)s_x;
    float a0 = 0.f, a1 = 0.f, a2 = 0.f, a3 = 0.f;
    #pragma unroll
    for (int m = 0; m < 4; ++m) {
      const float4 x4 = vin[m * 64 + lane];
      a0 += wr[0][m].x * x4.x + wr[0][m].y * x4.y + wr[0][m].z * x4.z + wr[0][m].w * x4.w;
      a1 += wr[1][m].x * x4.x + wr[1][m].y * x4.y + wr[1][m].z * x4.z + wr[1][m].w * x4.w;
      a2 += wr[2][m].x * x4.x + wr[2][m].y * x4.y + wr[2][m].z * x4.z + wr[2][m].w * x4.w;
      a3 += wr[3][m].x * x4.x + wr[3][m].y * x4.y + wr[3][m].z * x4.z + wr[3][m].w * x4.w;
    }
    #pragma unroll
    for (int off = 32; off; off >>= 1) {
      a0 += __shfl_down(a0, off, 64);
      a1 += __shfl_down(a1, off, 64);
      a2 += __shfl_down(a2, off, 64);
      a3 += __shfl_down(a3, off, 64);
    }
    if (lane == 0) {
      s_gd[dl][dq][dh][0] = a0; s_gd[dl][dq][dh][1] = a1;
      s_gd[dl][dq][dh][2] = a2; s_gd[dl][dq][dh][3] = a3;
    }
  };

  // 16-lane parallel LSTM epilogue (wave 0) — one transcendental chain deep
  // (R10-proven). Publishes h[t][l] for this block's 4 units.
  auto epilogue = [&](int l, int t) {
    if (w == 0 && lane < 16) {
      const int q = lane >> 2, u = lane & 3;
      const float g = s_gd[l][q][0][u] + s_gd[l][q][1][u] + s_bias[l][q][u];
      const float act = (q == 2) ? tanhf(g) : sigm(g);
      const float ai = __shfl(act, u, 64);
      const float af = __shfl(act, 4 + u, 64);
      const float ag = __shfl(act, 8 + u, 64);
      const float ao = __shfl(act, 12 + u, 64);
      if (lane < 4) {
        const float cn = af * s_c[l][lane] + ai * ag;
        s_c[l][lane] = cn;
        cstore(&HH[((size_t)t * L_ + l) * H_ + b * 4 + lane], ao * tanhf(cn));
      }
    }
  };

  // prefetch step-0 We operands (drained harmlessly at phase-A barrier)
  float4 wlog = *(const float4*)&We[((size_t)(b * 4 + (tid >> 8))) * H_ + (tid & 255) * 4];
  float4 wfb  = *(const float4*)&We[(size_t)tid * H_ + cswz];

  for (int t = 0; t < T_; ++t) {
    // ===== phase A: poll xv(t); l0 x-half; publish h0(t) =====
    if (t == 0) {
      if (tid < 256) *(float4*)&s_x[4 * tid] = make_float4(0.f, 0.f, 0.f, 0.f);
    } else if (tid < 256) {
      const float4 v = poll4(&XV[(size_t)t * H_ + 4 * tid]);
      *(float4*)&s_x[4 * tid] = v;
    }
    __syncthreads();
    if (wl == 0 && wh == 0) dot_to(0, wq, 0);
    __syncthreads();
    epilogue(0, t);   // publish h0(t); h-half partials came from B of t-1

    // ===== phase B: poll h0(t); l1 x-half (critical) + l0 h-half (t+1) =====
    if (tid < 256) {
      const float4 v = poll4(&HH[((size_t)t * L_ + 0) * H_ + 4 * tid]);
      *(float4*)&s_x[4 * tid] = v;
    }
    __syncthreads();
    if (wl == 1 && wh == 0) dot_to(1, wq, 0);  // critical
    if (wl == 0 && wh == 1) dot_to(0, wq, 1);  // for t+1
    __syncthreads();
    epilogue(1, t);   // publish h1(t); h-half partials came from C of t-1

    // ===== phase C: poll h1(t); logits rows + l1 h-half (t+1) =====
    if (tid < 256) {
      const float4 v = poll4(&HH[((size_t)t * L_ + 1) * H_ + 4 * tid]);
      *(float4*)&s_x[4 * tid] = v;
    }
    __syncthreads();
    {
      const float4 h4 = ((const float4*)s_x)[tid & 255];
      float a = wlog.x * h4.x + wlog.y * h4.y + wlog.z * h4.z + wlog.w * h4.w;
      #pragma unroll
      for (int off = 32; off; off >>= 1) a += __shfl_down(a, off, 64);
      if (lane == 0) s_red[w] = a;
    }
    if (wl == 1 && wh == 1) dot_to(1, wq, 1);  // for t+1
    __syncthreads();
    if (tid < 4)   // sum the 4 wave-partials per row -> publish logits
      cstore(&LG[(size_t)t * E_ + b * 4 + tid],
             s_red[tid * 4] + s_red[tid * 4 + 1] + s_red[tid * 4 + 2]
           + s_red[tid * 4 + 3] + s_be[t * 4 + tid]);

    // ===== phase D (fused, 2 barriers): poll lg(t); exp + feedback reduce;
    //       out; publish xv(t+1) = (sum ev*wfb)/Z =====
    if (tid < 256) {
      const float4 v = poll4(&LG[(size_t)t * E_ + 4 * tid]);
      *(float4*)&s_x[4 * tid] = v;
    }
    __syncthreads();
    {
      // |logits| = O(1) here (h in (-1,1), scaled We): exp without max-
      // subtraction cannot overflow; R10 validated this path (absmax 0).
      const float ev = expf(s_x[tid]);      // e = tid
      float sv = ev;
      float4 ac = make_float4(ev * wfb.x, ev * wfb.y, ev * wfb.z, ev * wfb.w);
      #pragma unroll
      for (int off = 32; off; off >>= 1) {   // joint 5-value reduce tree
        sv   += __shfl_down(sv,   off, 64);
        ac.x += __shfl_down(ac.x, off, 64);
        ac.y += __shfl_down(ac.y, off, 64);
        ac.z += __shfl_down(ac.z, off, 64);
        ac.w += __shfl_down(ac.w, off, 64);
      }
      if (lane == 0) { s_reds[w] = sv; s_part4[w] = ac; }
      __syncthreads();
      if ((tid >> 2) == b) {   // block b writes its 4 decision outputs
        float ss = 0.f;
        #pragma unroll
        for (int k = 0; k < 16; ++k) ss += s_reds[k];
        out[(size_t)t * E_ + tid] = ev / ss;
      }
      if (tid < 4) {           // publish x(t+1) for this block's 4 columns
        float ss = 0.f, s = 0.f;
        #pragma unroll
        for (int k = 0; k < 16; ++k) {
          ss += s_reds[k];
          s  += ((const float*)&s_part4[k])[tid];
        }
        cstore(&XV[(size_t)(t + 1) * H_ + cswz + tid], s / ss);
      }
    }

    // issue next step's We prefetch AFTER the last use of wlog/wfb:
    // drains during the next phase-A poll, never inside a hop.
    if (t + 1 < T_) {
      const float* Wn = We + (size_t)(t + 1) * E_ * H_;
      wlog = *(const float4*)&Wn[((size_t)(b * 4 + (tid >> 8))) * H_ + (tid & 255) * 4];
      wfb  = *(const float4*)&Wn[(size_t)tid * H_ + cswz];
    }
  }
}

extern "C" void kernel_launch(void* const* d_in, const int* in_sizes, int n_in,
                              void* d_out, int out_size, void* d_ws, size_t ws_size,
                              hipStream_t stream) {
  const float* W_ih = (const float*)d_in[0];
  const float* W_hh = (const float*)d_in[1];
  const float* b_ih = (const float*)d_in[2];
  const float* b_hh = (const float*)d_in[3];
  const float* We   = (const float*)d_in[4];
  const float* be   = (const float*)d_in[5];
  float* out = (float*)d_out;
  float* ws  = (float*)d_ws;

  // sentinel-fill all dataflow slots (graph-capturable, replayed every call)
  (void)hipMemsetAsync(ws, 0xFF, WS_BYTES, stream);

  void* args[] = {(void*)&W_ih, (void*)&W_hh, (void*)&b_ih, (void*)&b_hh,
                  (void*)&We,   (void*)&be,   (void*)&out,  (void*)&ws};
  (void)hipLaunchCooperativeKernel((const void*)ctrl_kernel, dim3(NB), dim3(BT),
                                   args, 0, stream);
}

// Round 15
// 992.000 us; speedup vs baseline: 1.2118x; 1.0600x over previous
//
#include <hip/hip_runtime.h>

static constexpr int L_ = 2;      // layers
static constexpr int H_ = 1024;   // hidden
static constexpr int E_ = 1024;   // embedding
static constexpr int T_ = 64;     // steps
static constexpr int NB = 256;    // blocks (== CUs)
static constexpr int BT = 1024;   // threads per block (16 waves)

// ws layout (floats) — pure dataflow, write-once per-step slots, NO flags.
// Sentinel-filled 0xFF per call; every produced value is finite, so
// "bits != 0xFFFFFFFF" == "data ready".
static constexpr int WS_XV = 0;                       // xv[T+1][H]
static constexpr int WS_H  = WS_XV + (T_ + 1) * H_;   // h[T][L][H]
static constexpr int WS_LG = WS_H + T_ * L_ * H_;     // lg[T][E]
static constexpr size_t WS_BYTES = (size_t)(WS_LG + T_ * E_) * 4;

static constexpr unsigned SENT = 0xFFFFFFFFu;

__device__ __forceinline__ float sigm(float v) { return 1.0f / (1.0f + expf(-v)); }

__device__ __forceinline__ unsigned cloadu(const float* p) {
  return __hip_atomic_load((const unsigned*)p, __ATOMIC_RELAXED, __HIP_MEMORY_SCOPE_AGENT);
}
__device__ __forceinline__ void cstore(float* p, float v) {
  __hip_atomic_store(p, v, __ATOMIC_RELAXED, __HIP_MEMORY_SCOPE_AGENT);
}
__device__ __forceinline__ float poll1(const float* p) {
  unsigned v = cloadu(p);
  while (v == SENT) { __builtin_amdgcn_s_sleep(1); v = cloadu(p); }
  return __uint_as_float(v);
}

// Weight-stationary, barrier-free, flag-free persistent controller.
// Wave w of block b permanently holds, in 64 registers (float4 wr[4][4]):
//   role (l = w>>3, q = (w>>1)&3, half = w&1 : 0=W_ih, 1=W_hh),
//   rows j = 4b+u (u=0..3), columns k = m*256 + lane*4 + {0..3}.
// Phase schedule (critical path has exactly 4 chip-wide hops/step):
//   A: poll xv(t)      -> l0 x-half dots            -> publish h0(t)
//   B: poll h0(t)      -> l1 x-half dots [critical]
//                         + l0 h-half dots for t+1  -> publish h1(t)
//   C: poll h1(t)      -> logits rows [all waves]
//                         + l1 h-half dots for t+1  -> publish lg(t)
//   D: poll lg(t)      -> softmax + out + feedback  -> publish xv(t+1)
//      then issue We(t+1) prefetch (after last barrier, so the loads can
//      only delay the next xv-poll consume, which is ~1us later anyway).
__global__ __launch_bounds__(BT, 4) void ctrl_kernel(
    const float* __restrict__ W_ih, const float* __restrict__ W_hh,
    const float* __restrict__ b_ih, const float* __restrict__ b_hh,
    const float* __restrict__ We,   const float* __restrict__ be,
    float* __restrict__ out, float* __restrict__ ws)
{
  const int tid  = threadIdx.x;
  const int b    = blockIdx.x;
  const int lane = tid & 63;
  const int w    = tid >> 6;       // wave 0..15
  const int wl   = w >> 3;         // layer of this wave's weights
  const int wq   = (w >> 1) & 3;   // gate index (i,f,g,o)
  const int wh   = w & 1;          // 0: W_ih half, 1: W_hh half

  float* xv = ws + WS_XV;
  float* hh = ws + WS_H;
  float* lg = ws + WS_LG;

  // feedback column ownership, XCD-swizzled
  const int cswz = ((b & 7) * 32 + (b >> 3)) * 4;

  __shared__ float  s_x[H_];            // staging: x / h0 / h1 / logits
  __shared__ float  s_gd[2][4][2][4];   // gate partials [l][q][half][unit]
  __shared__ float  s_bias[2][4][4];    // combined biases [l][q][unit]
  __shared__ float  s_be[T_ * 4];       // be rows for this block, all steps
  __shared__ float  s_c[2][4];          // cell state [l][unit]
  __shared__ float  s_red[16];          // logits reduction scratch
  __shared__ float  s_redm[16];         // softmax max partials
  __shared__ float  s_reds[16];         // softmax sum partials
  __shared__ float4 s_part4[16];        // x_next per-wave partials

  // ---- prologue ----
  if (tid < 32) {
    const int l = tid >> 4, q = (tid >> 2) & 3, u = tid & 3;
    const int j = b * 4 + u;
    s_bias[l][q][u] = b_ih[(size_t)l * 4 * H_ + q * H_ + j]
                    + b_hh[(size_t)l * 4 * H_ + q * H_ + j];
  }
  if (tid < 8) s_c[tid >> 2][tid & 3] = 0.0f;
  if (tid < 64) ((float*)s_gd)[tid] = 0.0f;   // h-half partials start at 0
  if (tid < T_ * 4)
    s_be[tid] = be[(size_t)(tid >> 2) * E_ + b * 4 + (tid & 3)];

  float4 wr[4][4];
  {
    const float* Wbase = (wh == 0) ? W_ih : W_hh;
    #pragma unroll
    for (int u = 0; u < 4; ++u) {
      const size_t row = (size_t)wl * 4 * H_ * H_
                       + ((size_t)wq * H_ + (size_t)(b * 4 + u)) * (size_t)H_;
      #pragma unroll
      for (int m = 0; m < 4; ++m)
        wr[u][m] = *(const float4*)&Wbase[row + (size_t)m * 256 + lane * 4];
    }
  }
  #pragma unroll
  for (int u = 0; u < 4; ++u)
    #pragma unroll
    for (int m = 0; m < 4; ++m)
      asm volatile("" : "+v"(wr[u][m].x), "+v"(wr[u][m].y),
                        "+v"(wr[u][m].z), "+v"(wr[u][m].w));

  // dot of this wave's held weight strip against vin, into s_gd[dl][dq][dh]
  auto dot_to = [&](const float4* vin, int dl, int dq, int dh) {
    float a0 = 0.f, a1 = 0.f, a2 = 0.f, a3 = 0.f;
    #pragma unroll
    for (int m = 0; m < 4; ++m) {
      const float4 x4 = vin[m * 64 + lane];
      a0 += wr[0][m].x * x4.x + wr[0][m].y * x4.y + wr[0][m].z * x4.z + wr[0][m].w * x4.w;
      a1 += wr[1][m].x * x4.x + wr[1][m].y * x4.y + wr[1][m].z * x4.z + wr[1][m].w * x4.w;
      a2 += wr[2][m].x * x4.x + wr[2][m].y * x4.y + wr[2][m].z * x4.z + wr[2][m].w * x4.w;
      a3 += wr[3][m].x * x4.x + wr[3][m].y * x4.y + wr[3][m].z * x4.z + wr[3][m].w * x4.w;
    }
    #pragma unroll
    for (int off = 32; off; off >>= 1) {
      a0 += __shfl_down(a0, off, 64);
      a1 += __shfl_down(a1, off, 64);
      a2 += __shfl_down(a2, off, 64);
      a3 += __shfl_down(a3, off, 64);
    }
    if (lane == 0) {
      s_gd[dl][dq][dh][0] = a0; s_gd[dl][dq][dh][1] = a1;
      s_gd[dl][dq][dh][2] = a2; s_gd[dl][dq][dh][3] = a3;
    }
  };

  // prefetch step-0 We operands (drained harmlessly at phase-A barrier)
  float4 wlog = *(const float4*)&We[((size_t)(b * 4 + (tid >> 8))) * H_ + (tid & 255) * 4];
  float4 wfb  = *(const float4*)&We[(size_t)tid * H_ + cswz];

  for (int t = 0; t < T_; ++t) {
    // ===== phase A: poll xv(t); l0 x-half; publish h0(t) =====
    if (t == 0) s_x[tid] = 0.0f;
    else        s_x[tid] = poll1(&xv[(size_t)t * H_ + tid]);
    __syncthreads();
    if (wl == 0 && wh == 0) dot_to((const float4*)s_x, 0, wq, 0);
    __syncthreads();
    if (tid < 4) {   // l0 epilogue (h-half partials came from phase B of t-1)
      const int u = tid;
      const float g0 = s_gd[0][0][0][u] + s_gd[0][0][1][u] + s_bias[0][0][u];
      const float g1 = s_gd[0][1][0][u] + s_gd[0][1][1][u] + s_bias[0][1][u];
      const float g2 = s_gd[0][2][0][u] + s_gd[0][2][1][u] + s_bias[0][2][u];
      const float g3 = s_gd[0][3][0][u] + s_gd[0][3][1][u] + s_bias[0][3][u];
      const float cn = sigm(g1) * s_c[0][u] + sigm(g0) * tanhf(g2);
      s_c[0][u] = cn;
      cstore(&hh[((size_t)t * L_ + 0) * H_ + b * 4 + u], sigm(g3) * tanhf(cn));
    }

    // ===== phase B: poll h0(t); l1 x-half (critical) + l0 h-half (t+1) =====
    s_x[tid] = poll1(&hh[((size_t)t * L_ + 0) * H_ + tid]);
    __syncthreads();
    if (wl == 1 && wh == 0) dot_to((const float4*)s_x, 1, wq, 0);  // critical
    if (wl == 0 && wh == 1) dot_to((const float4*)s_x, 0, wq, 1);  // for t+1
    __syncthreads();
    if (tid < 4) {   // l1 epilogue (h-half partials came from phase C of t-1)
      const int u = tid;
      const float g0 = s_gd[1][0][0][u] + s_gd[1][0][1][u] + s_bias[1][0][u];
      const float g1 = s_gd[1][1][0][u] + s_gd[1][1][1][u] + s_bias[1][1][u];
      const float g2 = s_gd[1][2][0][u] + s_gd[1][2][1][u] + s_bias[1][2][u];
      const float g3 = s_gd[1][3][0][u] + s_gd[1][3][1][u] + s_bias[1][3][u];
      const float cn = sigm(g1) * s_c[1][u] + sigm(g0) * tanhf(g2);
      s_c[1][u] = cn;
      cstore(&hh[((size_t)t * L_ + 1) * H_ + b * 4 + u], sigm(g3) * tanhf(cn));
    }

    // ===== phase C: poll h1(t); logits rows + l1 h-half (t+1) =====
    s_x[tid] = poll1(&hh[((size_t)t * L_ + 1) * H_ + tid]);
    __syncthreads();
    {
      const float4 h4 = ((const float4*)s_x)[tid & 255];
      float a = wlog.x * h4.x + wlog.y * h4.y + wlog.z * h4.z + wlog.w * h4.w;
      #pragma unroll
      for (int off = 32; off; off >>= 1) a += __shfl_down(a, off, 64);
      if (lane == 0) s_red[w] = a;
    }
    if (wl == 1 && wh == 1) dot_to((const float4*)s_x, 1, wq, 1);  // for t+1
    __syncthreads();
    if (tid < 4) {   // sum the 4 wave-partials per row -> publish logits
      const float v = s_red[tid * 4] + s_red[tid * 4 + 1] + s_red[tid * 4 + 2]
                    + s_red[tid * 4 + 3] + s_be[t * 4 + tid];
      cstore(&lg[(size_t)t * E_ + b * 4 + tid], v);
    }

    // ===== phase D: poll lg(t); softmax + out + feedback; publish xv(t+1) =====
    s_x[tid] = poll1(&lg[(size_t)t * E_ + tid]);
    __syncthreads();
    {
      const float v = s_x[tid];
      float mm = v;
      #pragma unroll
      for (int off = 32; off; off >>= 1) mm = fmaxf(mm, __shfl_down(mm, off, 64));
      if (lane == 0) s_redm[w] = mm;
      __syncthreads();
      mm = s_redm[0];
      #pragma unroll
      for (int k = 1; k < 16; ++k) mm = fmaxf(mm, s_redm[k]);
      const float ev = expf(v - mm);        // e = tid
      float sv = ev;
      #pragma unroll
      for (int off = 32; off; off >>= 1) sv += __shfl_down(sv, off, 64);
      if (lane == 0) s_reds[w] = sv;
      __syncthreads();
      float ssum = 0.f;
      #pragma unroll
      for (int k = 0; k < 16; ++k) ssum += s_reds[k];
      const float inv = 1.0f / ssum;
      const float d = ev * inv;             // decision[e = tid], all blocks agree

      if ((tid >> 2) == b) out[(size_t)t * E_ + tid] = d;  // block b writes its 4

      float4 acc = make_float4(d * wfb.x, d * wfb.y, d * wfb.z, d * wfb.w);
      #pragma unroll
      for (int off = 32; off; off >>= 1) {
        acc.x += __shfl_down(acc.x, off, 64);
        acc.y += __shfl_down(acc.y, off, 64);
        acc.z += __shfl_down(acc.z, off, 64);
        acc.w += __shfl_down(acc.w, off, 64);
      }
      if (lane == 0) s_part4[w] = acc;
      __syncthreads();
      if (tid < 4) {
        float s = 0.f;
        #pragma unroll
        for (int k = 0; k < 16; ++k)
          s += ((const float*)&s_part4[k])[tid];
        cstore(&xv[(size_t)(t + 1) * H_ + cswz + tid], s);  // x for step t+1
      }
    }

    // issue next step's We prefetch AFTER the last barrier of the step:
    // these loads can only delay the next xv-poll consume (~1us later),
    // never a mid-step hop (in-order vmcnt, the R6/R7 failure mode).
    if (t + 1 < T_) {
      const float* Wn = We + (size_t)(t + 1) * E_ * H_;
      wlog = *(const float4*)&Wn[((size_t)(b * 4 + (tid >> 8))) * H_ + (tid & 255) * 4];
      wfb  = *(const float4*)&Wn[(size_t)tid * H_ + cswz];
    }
  }
}

extern "C" void kernel_launch(void* const* d_in, const int* in_sizes, int n_in,
                              void* d_out, int out_size, void* d_ws, size_t ws_size,
                              hipStream_t stream) {
  const float* W_ih = (const float*)d_in[0];
  const float* W_hh = (const float*)d_in[1];
  const float* b_ih = (const float*)d_in[2];
  const float* b_hh = (const float*)d_in[3];
  const float* We   = (const float*)d_in[4];
  const float* be   = (const float*)d_in[5];
  float* out = (float*)d_out;
  float* ws  = (float*)d_ws;

  // sentinel-fill all dataflow slots (graph-capturable, replayed every call)
  (void)hipMemsetAsync(ws, 0xFF, WS_BYTES, stream);

  void* args[] = {(void*)&W_ih, (void*)&W_hh, (void*)&b_ih, (void*)&b_hh,
                  (void*)&We,   (void*)&be,   (void*)&out,  (void*)&ws};
  (void)hipLaunchCooperativeKernel((const void*)ctrl_kernel, dim3(NB), dim3(BT),
                                   args, 0, stream);
}